// Round 11
// baseline (35.856 us; speedup 1.0000x reference)
//
#include <hip/hip_runtime.h>
#include <hip/hip_bf16.h>
#include <math.h>

#define HWV (1080 * 1920)
#define NROWS 4

typedef _Float16 half2 __attribute__((ext_vector_type(2)));
typedef __fp16   pk2   __attribute__((ext_vector_type(2)));
union U32H2 { unsigned u; half2 h; pk2 p; };

// ---------------------------------------------------------------------------
// Weight prep (1 block): fold BN, pack f16 weights duplicated per lane-pair.
//   [64..79] = w2 (f32)   [80] = b2
//   u32 wp = (unsigned*)(wsw+84): wp[4c+{0,1,2,3}] = {wr,wr},{wg,wg},{wb,wb},{bs,bs}
// ---------------------------------------------------------------------------
__global__ void prep_w(const float* __restrict__ w1, const float* __restrict__ b1,
                       const float* __restrict__ gamma, const float* __restrict__ beta,
                       const float* __restrict__ mean, const float* __restrict__ var,
                       const float* __restrict__ w2, const float* __restrict__ b2,
                       float* __restrict__ wsw) {
    int i = threadIdx.x;
    if (i < 16) {
        float inv = gamma[i] / sqrtf(var[i] + 1e-5f);
        float wr = w1[i*3+0] * inv, wg = w1[i*3+1] * inv, wb = w1[i*3+2] * inv;
        float bs = (b1[i] - mean[i]) * inv + beta[i];
        wsw[64 + i] = w2[i];
        unsigned* wp = (unsigned*)(wsw + 84);
        U32H2 t;
        t.p = __builtin_amdgcn_cvt_pkrtz(wr, wr); wp[i*4+0] = t.u;
        t.p = __builtin_amdgcn_cvt_pkrtz(wg, wg); wp[i*4+1] = t.u;
        t.p = __builtin_amdgcn_cvt_pkrtz(wb, wb); wp[i*4+2] = t.u;
        t.p = __builtin_amdgcn_cvt_pkrtz(bs, bs); wp[i*4+3] = t.u;
    }
    if (i == 0) wsw[80] = b2[0];
}

// ---------------------------------------------------------------------------
// Persistent 4-row blocks, double-buffered row pipeline.
// Block = 512 threads, 2 px/thread, 1024-px x-segment, rows yb..yb+3.
// Per row: issue next-row grid+fullres loads -> compute current row from LDS
// -> write next-row stage to alternate buffer -> barrier.
// ---------------------------------------------------------------------------
__global__ __launch_bounds__(512, 8) void fused_kernel(
        const float* __restrict__ fullres,
        const float* __restrict__ grid,
        const float* __restrict__ wsw,
        float* __restrict__ out) {
    __shared__ unsigned slo[2][9][9][4];   // [buf][cell][z][ch-pairs 0..3]
    __shared__ unsigned shi[2][9][9][2];   // [buf][cell][z][ch-pairs 4..5]

    const int tid = threadIdx.x;
    const int seg = blockIdx.x;            // 0..1
    const int n   = blockIdx.y;            // 0..1
    const int yb  = blockIdx.z * NROWS;    // 0,4,...,1076
    const int xs  = seg * 1024;
    const int x   = xs + 2 * tid;
    const bool act = (x < 1920);
    const int a = (int)((float)xs * (15.0f / 1919.0f));
    const int pcol = min(x, 1918);

    // staging decomposition (fixed per thread)
    const bool sact = (tid < 486);
    int sj = 0, sz = 0, sk = 0;
    const float* sq0 = grid;               // base ptr, y-independent part
    if (sact) {
        sj = tid / 81;
        int rem = tid - sj * 81;
        sz = rem / 9;
        sk = rem - sz * 9;
        int szz = min(sz, 7);
        int sxc = min(a + sk, 15);
        sq0 = grid + n * 24576 + (2 * sj) * 2048 + szz * 256 + sxc;
    }

    float sv0, sv1, sv2, sv3, sty;
    auto stage_load = [&](int y) {
        float gy = (float)y * (15.0f / 1079.0f);
        float y0f = floorf(gy);
        sty = gy - y0f;
        int y0 = min((int)y0f, 15);
        int y1 = min(y0 + 1, 15);
        if (sact) {
            const float* q0 = sq0 + y0 * 16;
            int dy = (y1 - y0) * 16;
            sv0 = q0[0];    sv1 = q0[dy];
            sv2 = q0[2048]; sv3 = q0[2048 + dy];
        }
    };
    auto stage_write = [&](int buf) {
        if (sact) {
            float e0 = fmaf(sty, sv1 - sv0, sv0);
            float e1 = fmaf(sty, sv3 - sv2, sv2);
            U32H2 t;
            t.p = __builtin_amdgcn_cvt_pkrtz(e0, e1);
            if (sj < 4) slo[buf][sk][sz][sj] = t.u;
            else        shi[buf][sk][sz][sj - 4] = t.u;
        }
    };
    auto fr_load = [&](int y, float2& R, float2& G, float2& B) {
        const float* fr = fullres + n * 3 * HWV + y * 1920 + pcol;
        R = *(const float2*)(fr);
        G = *(const float2*)(fr + HWV);
        B = *(const float2*)(fr + 2 * HWV);
    };

    const unsigned* wp = (const unsigned*)(wsw + 84);
    const half2 zero = {(_Float16)0.0f, (_Float16)0.0f};
    const float b2s = wsw[80];

    // ---- prologue: stage row yb ----
    float2 R, G, B;
    stage_load(yb);
    fr_load(yb, R, G, B);
    stage_write(0);
    __syncthreads();

    int cur = 0;
#pragma unroll
    for (int rrow = 0; rrow < NROWS; ++rrow) {
        const int y = yb + rrow;
        const int p = y * 1920 + pcol;

        // issue next-row loads early (latency hides under this row's compute)
        float2 Rn, Gn, Bn;
        if (rrow + 1 < NROWS) {
            stage_load(y + 1);
            fr_load(y + 1, Rn, Gn, Bn);
        }

        if (act) {
            // ---- guide MLP: both pixels share packed weight regs ----
            U32H2 rr, gg, bb;
            rr.p = __builtin_amdgcn_cvt_pkrtz(R.x, R.y);
            gg.p = __builtin_amdgcn_cvt_pkrtz(G.x, G.y);
            bb.p = __builtin_amdgcn_cvt_pkrtz(B.x, B.y);
            float acc0 = b2s, acc1 = b2s;
#pragma unroll
            for (int c = 0; c < 16; ++c) {
                U32H2 wr, wg, wb, bs;
                wr.u = wp[4*c+0]; wg.u = wp[4*c+1]; wb.u = wp[4*c+2]; bs.u = wp[4*c+3];
                half2 h = wr.h * rr.h + (wg.h * gg.h + (wb.h * bb.h + bs.h));
                h = __builtin_elementwise_max(h, zero);
                float w2c = wsw[64 + c];
                acc0 = fmaf((float)h.x, w2c, acc0);
                acc1 = fmaf((float)h.y, w2c, acc1);
            }

            float accv[2] = {acc0, acc1};
            float rv[2] = {R.x, R.y}, gv[2] = {G.x, G.y}, bv[2] = {B.x, B.y};
            float outr[2], outg[2], outb[2];

#pragma unroll
            for (int q = 0; q < 2; ++q) {
                float e = __expf(-accv[q]);
                float guide = __builtin_amdgcn_rcpf(1.0f + e);
                float gz = guide * 7.0f;
                float z0f = floorf(gz);
                float tz = gz - z0f;
                int z0 = min((int)z0f, 7);
                int z1 = z0 + 1;               // slot 8 duplicates z=7

                float gx = (float)(x + q) * (15.0f / 1919.0f);
                float x0f = floorf(gx);
                float tx = gx - x0f;
                int x0 = (int)x0f;
                int k0 = x0 - a;
                int k1 = min(x0 + 1, 15) - a;

                float wx0 = 1.0f - tx, wx1 = tx;
                float wz0 = 1.0f - tz, wz1 = tz;

                U32H2 w00h, w01h, w10h, w11h;
                w00h.p = __builtin_amdgcn_cvt_pkrtz(wx0 * wz0, wx0 * wz0);
                w01h.p = __builtin_amdgcn_cvt_pkrtz(wx0 * wz1, wx0 * wz1);
                w10h.p = __builtin_amdgcn_cvt_pkrtz(wx1 * wz0, wx1 * wz0);
                w11h.p = __builtin_amdgcn_cvt_pkrtz(wx1 * wz1, wx1 * wz1);

                const uint4 A0 = *(const uint4*)&slo[cur][k0][z0][0];
                const uint4 A1 = *(const uint4*)&slo[cur][k0][z1][0];
                const uint4 B0 = *(const uint4*)&slo[cur][k1][z0][0];
                const uint4 B1 = *(const uint4*)&slo[cur][k1][z1][0];
                const uint2 C0 = *(const uint2*)&shi[cur][k0][z0][0];
                const uint2 C1 = *(const uint2*)&shi[cur][k0][z1][0];
                const uint2 D0 = *(const uint2*)&shi[cur][k1][z0][0];
                const uint2 D1 = *(const uint2*)&shi[cur][k1][z1][0];

                unsigned a0j[6] = {A0.x, A0.y, A0.z, A0.w, C0.x, C0.y};
                unsigned a1j[6] = {A1.x, A1.y, A1.z, A1.w, C1.x, C1.y};
                unsigned b0j[6] = {B0.x, B0.y, B0.z, B0.w, D0.x, D0.y};
                unsigned b1j[6] = {B1.x, B1.y, B1.z, B1.w, D1.x, D1.y};

                half2 hc[6];
#pragma unroll
                for (int j = 0; j < 6; ++j) {
                    U32H2 ua0, ua1, ub0, ub1;
                    ua0.u = a0j[j]; ua1.u = a1j[j]; ub0.u = b0j[j]; ub1.u = b1j[j];
                    half2 h = w00h.h * ua0.h + (w01h.h * ua1.h);
                    h = w10h.h * ub0.h + h;
                    h = w11h.h * ub1.h + h;
                    hc[j] = h;
                }

                outr[q] = fmaf((float)hc[0].x, rv[q], fmaf((float)hc[0].y, gv[q],
                          fmaf((float)hc[1].x, bv[q], (float)hc[1].y)));
                outg[q] = fmaf((float)hc[2].x, rv[q], fmaf((float)hc[2].y, gv[q],
                          fmaf((float)hc[3].x, bv[q], (float)hc[3].y)));
                outb[q] = fmaf((float)hc[4].x, rv[q], fmaf((float)hc[4].y, gv[q],
                          fmaf((float)hc[5].x, bv[q], (float)hc[5].y)));
            }

            float* op = out + n * 3 * HWV + p;
            *(float2*)(op)           = make_float2(outr[0], outr[1]);
            *(float2*)(op + HWV)     = make_float2(outg[0], outg[1]);
            *(float2*)(op + 2 * HWV) = make_float2(outb[0], outb[1]);
        }

        // ---- write next-row stage into alternate buffer ----
        if (rrow + 1 < NROWS) {
            stage_write(cur ^ 1);
        }
        __syncthreads();
        cur ^= 1;
        R = Rn; G = Gn; B = Bn;
    }
}

extern "C" void kernel_launch(void* const* d_in, const int* in_sizes, int n_in,
                              void* d_out, int out_size, void* d_ws, size_t ws_size,
                              hipStream_t stream) {
    const float* fullres = (const float*)d_in[0];
    const float* grid    = (const float*)d_in[1];
    const float* w1      = (const float*)d_in[2];
    const float* b1      = (const float*)d_in[3];
    const float* gamma   = (const float*)d_in[4];
    const float* beta    = (const float*)d_in[5];
    const float* mean    = (const float*)d_in[6];
    const float* var     = (const float*)d_in[7];
    const float* w2      = (const float*)d_in[8];
    const float* b2      = (const float*)d_in[9];
    float* out = (float*)d_out;

    float* wsw = (float*)d_ws;   // 148 floats used

    prep_w<<<1, 64, 0, stream>>>(w1, b1, gamma, beta, mean, var, w2, b2, wsw);

    dim3 grid_dim(2, 2, 1080 / NROWS);   // seg x img x row-groups = 1080 blocks
    fused_kernel<<<grid_dim, 512, 0, stream>>>(fullres, grid, wsw, out);
}

// Round 12
// 32.605 us; speedup vs baseline: 1.0997x; 1.0997x over previous
//
#include <hip/hip_runtime.h>
#include <hip/hip_bf16.h>
#include <math.h>

#define HWV (1080 * 1920)

typedef _Float16 half2 __attribute__((ext_vector_type(2)));
typedef __fp16   pk2   __attribute__((ext_vector_type(2)));
union U32H2 { unsigned u; half2 h; pk2 p; };

// ---------------------------------------------------------------------------
// Weight prep (1 block): fold BN, pack f16 weights duplicated per lane-pair.
//   [64..79] = w2 (f32)   [80] = b2
//   u32 wp = (unsigned*)(wsw+84): wp[4c+{0,1,2,3}] = {wr,wr},{wg,wg},{wb,wb},{bs,bs}
// ---------------------------------------------------------------------------
__global__ void prep_w(const float* __restrict__ w1, const float* __restrict__ b1,
                       const float* __restrict__ gamma, const float* __restrict__ beta,
                       const float* __restrict__ mean, const float* __restrict__ var,
                       const float* __restrict__ w2, const float* __restrict__ b2,
                       float* __restrict__ wsw) {
    int i = threadIdx.x;
    if (i < 16) {
        float inv = gamma[i] / sqrtf(var[i] + 1e-5f);
        float wr = w1[i*3+0] * inv, wg = w1[i*3+1] * inv, wb = w1[i*3+2] * inv;
        float bs = (b1[i] - mean[i]) * inv + beta[i];
        wsw[64 + i] = w2[i];
        unsigned* wp = (unsigned*)(wsw + 84);
        U32H2 t;
        t.p = __builtin_amdgcn_cvt_pkrtz(wr, wr); wp[i*4+0] = t.u;
        t.p = __builtin_amdgcn_cvt_pkrtz(wg, wg); wp[i*4+1] = t.u;
        t.p = __builtin_amdgcn_cvt_pkrtz(wb, wb); wp[i*4+2] = t.u;
        t.p = __builtin_amdgcn_cvt_pkrtz(bs, bs); wp[i*4+3] = t.u;
    }
    if (i == 0) wsw[80] = b2[0];
}

// ---------------------------------------------------------------------------
// Fused kernel. Block = 256 threads x 4 px = 1024-px x-segment of one row.
// Stage y-lerped f16 channel-pair slab from original grid layout into LDS
// (z=7 duplicated into slot 8). 4 independent per-pixel chains per thread.
// ---------------------------------------------------------------------------
__global__ __launch_bounds__(256, 8) void fused_kernel(
        const float* __restrict__ fullres,
        const float* __restrict__ grid,
        const float* __restrict__ wsw,
        float* __restrict__ out) {
    __shared__ unsigned slo[9][9][4];   // [cell][z][ch-pairs 0..3]
    __shared__ unsigned shi[9][9][2];   // [cell][z][ch-pairs 4..5]

    const int tid = threadIdx.x;
    const int seg = blockIdx.x;
    const int n   = blockIdx.z;
    const int y   = blockIdx.y;
    const int xs  = seg * 1024;
    const int x   = xs + 4 * tid;
    const bool act = (x < 1920);
    const int a = (int)((float)xs * (15.0f / 1919.0f));
    const int pcol = min(x, 1916);
    const int p = y * 1920 + pcol;

    // ---- prefetch fullres (issued first; latency hides under staging) ----
    const float* fr = fullres + n * 3 * HWV + p;
    float4 R = *(const float4*)(fr);
    float4 G = *(const float4*)(fr + HWV);
    float4 B = *(const float4*)(fr + 2 * HWV);

    // ---- stage: 9 cells x 9 z x 6 ch-pairs from original layout ----
    {
        float gy = (float)y * (15.0f / 1079.0f);
        float y0f = floorf(gy);
        float ty = gy - y0f;
        int y0 = min((int)y0f, 15);
        int y1 = min(y0 + 1, 15);
        const int dy = (y1 - y0) * 16;
        const float* gb = grid + n * 24576 + y0 * 16;
#pragma unroll
        for (int idx = tid; idx < 486; idx += 256) {
            int j   = idx / 81;           // ch-pair 0..5
            int rem = idx - j * 81;
            int z   = rem / 9;            // 0..8
            int k   = rem - z * 9;        // cell 0..8
            int zz  = min(z, 7);
            int xc  = min(a + k, 15);
            const float* q0 = gb + (2 * j) * 2048 + zz * 256 + xc;
            const float* q1 = q0 + 2048;
            float v00 = q0[0], v01 = q0[dy];
            float v10 = q1[0], v11 = q1[dy];
            float e0 = fmaf(ty, v01 - v00, v00);
            float e1 = fmaf(ty, v11 - v10, v10);
            U32H2 t;
            t.p = __builtin_amdgcn_cvt_pkrtz(e0, e1);
            if (j < 4) slo[k][z][j] = t.u;
            else       shi[k][z][j - 4] = t.u;
        }
    }
    __syncthreads();

    if (!act) return;

    // ---- guide MLP: 4 px as two packed pairs, shared SGPR weights ----
    U32H2 r01, r23, g01, g23, b01, b23;
    r01.p = __builtin_amdgcn_cvt_pkrtz(R.x, R.y);
    r23.p = __builtin_amdgcn_cvt_pkrtz(R.z, R.w);
    g01.p = __builtin_amdgcn_cvt_pkrtz(G.x, G.y);
    g23.p = __builtin_amdgcn_cvt_pkrtz(G.z, G.w);
    b01.p = __builtin_amdgcn_cvt_pkrtz(B.x, B.y);
    b23.p = __builtin_amdgcn_cvt_pkrtz(B.z, B.w);
    const unsigned* wp = (const unsigned*)(wsw + 84);
    const half2 zero = {(_Float16)0.0f, (_Float16)0.0f};
    const float b2s = wsw[80];
    float acc0 = b2s, acc1 = b2s, acc2 = b2s, acc3 = b2s;
#pragma unroll
    for (int c = 0; c < 16; ++c) {
        U32H2 wr, wg, wb, bs;
        wr.u = wp[4*c+0]; wg.u = wp[4*c+1]; wb.u = wp[4*c+2]; bs.u = wp[4*c+3];
        half2 h01 = wr.h * r01.h + (wg.h * g01.h + (wb.h * b01.h + bs.h));
        half2 h23 = wr.h * r23.h + (wg.h * g23.h + (wb.h * b23.h + bs.h));
        h01 = __builtin_elementwise_max(h01, zero);
        h23 = __builtin_elementwise_max(h23, zero);
        float w2c = wsw[64 + c];
        acc0 = fmaf((float)h01.x, w2c, acc0);
        acc1 = fmaf((float)h01.y, w2c, acc1);
        acc2 = fmaf((float)h23.x, w2c, acc2);
        acc3 = fmaf((float)h23.y, w2c, acc3);
    }

    float accv[4] = {acc0, acc1, acc2, acc3};
    float rv[4] = {R.x, R.y, R.z, R.w};
    float gv[4] = {G.x, G.y, G.z, G.w};
    float bv[4] = {B.x, B.y, B.z, B.w};
    float outr[4], outg[4], outb[4];

#pragma unroll
    for (int q = 0; q < 4; ++q) {
        float e = __expf(-accv[q]);
        float guide = __builtin_amdgcn_rcpf(1.0f + e);
        float gz = guide * 7.0f;
        float z0f = floorf(gz);
        float tz = gz - z0f;
        int z0 = min((int)z0f, 7);
        int z1 = z0 + 1;               // slot 8 duplicates z=7

        float gx = (float)(x + q) * (15.0f / 1919.0f);
        float x0f = floorf(gx);
        float tx = gx - x0f;
        int x0 = (int)x0f;
        int k0 = x0 - a;
        int k1 = min(x0 + 1, 15) - a;

        float wx0 = 1.0f - tx, wx1 = tx;
        float wz0 = 1.0f - tz, wz1 = tz;

        U32H2 w00h, w01h, w10h, w11h;
        w00h.p = __builtin_amdgcn_cvt_pkrtz(wx0 * wz0, wx0 * wz0);
        w01h.p = __builtin_amdgcn_cvt_pkrtz(wx0 * wz1, wx0 * wz1);
        w10h.p = __builtin_amdgcn_cvt_pkrtz(wx1 * wz0, wx1 * wz0);
        w11h.p = __builtin_amdgcn_cvt_pkrtz(wx1 * wz1, wx1 * wz1);

        const uint4 A0 = *(const uint4*)&slo[k0][z0][0];
        const uint4 A1 = *(const uint4*)&slo[k0][z1][0];
        const uint4 B0 = *(const uint4*)&slo[k1][z0][0];
        const uint4 B1 = *(const uint4*)&slo[k1][z1][0];
        const uint2 C0 = *(const uint2*)&shi[k0][z0][0];
        const uint2 C1 = *(const uint2*)&shi[k0][z1][0];
        const uint2 D0 = *(const uint2*)&shi[k1][z0][0];
        const uint2 D1 = *(const uint2*)&shi[k1][z1][0];

        unsigned a0j[6] = {A0.x, A0.y, A0.z, A0.w, C0.x, C0.y};
        unsigned a1j[6] = {A1.x, A1.y, A1.z, A1.w, C1.x, C1.y};
        unsigned b0j[6] = {B0.x, B0.y, B0.z, B0.w, D0.x, D0.y};
        unsigned b1j[6] = {B1.x, B1.y, B1.z, B1.w, D1.x, D1.y};

        half2 hc[6];
#pragma unroll
        for (int j = 0; j < 6; ++j) {
            U32H2 ua0, ua1, ub0, ub1;
            ua0.u = a0j[j]; ua1.u = a1j[j]; ub0.u = b0j[j]; ub1.u = b1j[j];
            half2 h = w00h.h * ua0.h + (w01h.h * ua1.h);
            h = w10h.h * ub0.h + h;
            h = w11h.h * ub1.h + h;
            hc[j] = h;
        }

        outr[q] = fmaf((float)hc[0].x, rv[q], fmaf((float)hc[0].y, gv[q],
                  fmaf((float)hc[1].x, bv[q], (float)hc[1].y)));
        outg[q] = fmaf((float)hc[2].x, rv[q], fmaf((float)hc[2].y, gv[q],
                  fmaf((float)hc[3].x, bv[q], (float)hc[3].y)));
        outb[q] = fmaf((float)hc[4].x, rv[q], fmaf((float)hc[4].y, gv[q],
                  fmaf((float)hc[5].x, bv[q], (float)hc[5].y)));
    }

    float* op = out + n * 3 * HWV + p;
    *(float4*)(op)           = make_float4(outr[0], outr[1], outr[2], outr[3]);
    *(float4*)(op + HWV)     = make_float4(outg[0], outg[1], outg[2], outg[3]);
    *(float4*)(op + 2 * HWV) = make_float4(outb[0], outb[1], outb[2], outb[3]);
}

extern "C" void kernel_launch(void* const* d_in, const int* in_sizes, int n_in,
                              void* d_out, int out_size, void* d_ws, size_t ws_size,
                              hipStream_t stream) {
    const float* fullres = (const float*)d_in[0];
    const float* grid    = (const float*)d_in[1];
    const float* w1      = (const float*)d_in[2];
    const float* b1      = (const float*)d_in[3];
    const float* gamma   = (const float*)d_in[4];
    const float* beta    = (const float*)d_in[5];
    const float* mean    = (const float*)d_in[6];
    const float* var     = (const float*)d_in[7];
    const float* w2      = (const float*)d_in[8];
    const float* b2      = (const float*)d_in[9];
    float* out = (float*)d_out;

    float* wsw = (float*)d_ws;   // 148 floats used

    prep_w<<<1, 64, 0, stream>>>(w1, b1, gamma, beta, mean, var, w2, b2, wsw);

    dim3 grid_dim(2, 1080, 2);   // seg x row x img = 4320 blocks of 256
    fused_kernel<<<grid_dim, 256, 0, stream>>>(fullres, grid, wsw, out);
}